// Round 8
// baseline (1805.914 us; speedup 1.0000x reference)
//
#include <hip/hip_runtime.h>
#include <hip/hip_bf16.h>

// SARDecoder round 16: attention folded back into the persistent kernel as
// role C (r5's pipeline structure on the r14-verified sysbar). Grid 160 =
// 64 A + 64 B + 32 C; C computes att(L-2) inside the barrier-wait bubble
// (input h1hist[L-1] guaranteed by barrier L-1; staged with system-scope
// loads). k_att kernel deleted (-260M trans ops of serial tail + 508MB L2
// re-reads now overlapped). Loop L=0..32, barriers 0..31 target (L+1)*160.
// m0: 4 independent accumulators (break 512-deep FMA chain). Conv, k_pre,
// A/B bodies, workspace byte-identical to r15.

#define RNN   512
#define V1    111
#define STEPS 31
#define HWP   256
#define POOLF 11008
#define NWG   160

typedef unsigned short ushortT;
typedef unsigned int   uintT;
typedef __attribute__((ext_vector_type(8))) short bf16x8;   // 8 bf16 (4 VGPRs)
typedef __attribute__((ext_vector_type(4))) float f32x4;

__device__ __forceinline__ float blo(uintT u){ union { uintT i; float f; } v; v.i = u << 16; return v.f; }
__device__ __forceinline__ float bhi(uintT u){ union { uintT i; float f; } v; v.i = u & 0xffff0000u; return v.f; }
__device__ __forceinline__ ushortT f2b(float f){
  __hip_bfloat16 h = __float2bfloat16(f);
  union { __hip_bfloat16 b; ushortT s; } v; v.b = h; return v.s;
}
__device__ __forceinline__ uintT packbf(float lo, float hi){
  return (uintT)f2b(lo) | ((uintT)f2b(hi) << 16);
}
__device__ __forceinline__ bf16x8 u4_to_b8(uint4 u){
  union { uint4 a; bf16x8 b; } v; v.a = u; return v.b;
}
__device__ __forceinline__ float sigf(float x){ return 1.f/(1.f + __expf(-x)); }
__device__ __forceinline__ float tanh_f(float x){ float e = __expf(2.f*x); return 1.f - 2.f/(e+1.f); }

// ---- SYSTEM-scope relaxed atomics: bypass L2 both directions (MALL-coherent) ----
__device__ __forceinline__ uintT sload_u(const uintT* p){
  return __hip_atomic_load((uintT*)p, __ATOMIC_RELAXED, __HIP_MEMORY_SCOPE_SYSTEM);
}
__device__ __forceinline__ void sstore_u(uintT* p, uintT v){
  __hip_atomic_store(p, v, __ATOMIC_RELAXED, __HIP_MEMORY_SCOPE_SYSTEM);
}

// ---------------- k_pre: featT (bid<10880) + tconv2 (grid 15488) ----------------
__global__ __launch_bounds__(256) void k_pre(const float* __restrict__ feat,
                                             const float* __restrict__ Wf,
                                             uintT* __restrict__ fT,
                                             uintT* __restrict__ wb){
  const int bid = blockIdx.x, tid = threadIdx.x;
  if (bid < 10880){
    int idx = bid*256 + tid;
    int cp = idx & 255;
    int r  = idx >> 8;
    int xi = r % 34;
    int q  = r / 34;
    int yy = q % 10;
    int b  = q / 10;
    float v0 = 0.f, v1 = 0.f;
    if (yy >= 1 && yy <= 8 && xi >= 1 && xi <= 32){
      size_t base = (((size_t)b*512 + 2*cp)*8 + (yy-1))*32 + (xi-1);
      v0 = feat[base];
      v1 = feat[base + 256];
    }
    fT[idx] = packbf(v0, v1);
  } else {
    int idx = (bid - 10880)*256 + tid;   // 1,179,648
    int cp = idx & 255;
    int r  = idx >> 8;
    int a  = r & 511;
    int t  = r >> 9;
    float v0 = Wf[((size_t)a*512 + 2*cp)*9 + t];
    float v1 = Wf[((size_t)a*512 + 2*cp + 1)*9 + t];
    wb[idx] = packbf(v0, v1);
  }
}

// ---------------- k_post: wgate | wstT | woutb | m0 | init (grid 8127) ----------------
__global__ __launch_bounds__(256) void k_post(
    const float* __restrict__ w0, const float* __restrict__ w1,
    const float* __restrict__ w2, uintT* __restrict__ wgb,
    const float* __restrict__ Wst, uintT* __restrict__ WstTb,
    const float* __restrict__ Wout, uintT* __restrict__ Woutb,
    const float* __restrict__ wih0, const float* __restrict__ Wemb,
    const float* __restrict__ bih0, const float* __restrict__ bhh0,
    float* __restrict__ M0,
    float* __restrict__ st, uintT* __restrict__ h1hist, uintT* __restrict__ bar)
{
  const int bid = blockIdx.x, tid = threadIdx.x;
  if (bid < 6144){
    int idx = bid*256 + tid;            // 1,572,864
    int m = idx >> 19, r = idx & 524287;
    const float* s = (m==0)? w0 : (m==1)? w1 : w2;
    float2 v = *(const float2*)(s + 2*(size_t)r);
    wgb[idx] = packbf(v.x, v.y);
  } else if (bid < 6656){
    int idx = (bid-6144)*256 + tid;     // 131,072
    int u = idx >> 8, ap = idx & 255;
    WstTb[idx] = packbf(Wst[(size_t)(2*ap)*512 + u], Wst[(size_t)(2*ap+1)*512 + u]);
  } else if (bid < 6878){
    int idx = (bid-6656)*256 + tid;     // 56,832
    float2 v = *(const float2*)(Wout + 2*(size_t)idx);
    Woutb[idx] = packbf(v.x, v.y);
  } else if (bid < 7902){
    int j = (bid-6878)*2 + (tid >> 7);  // 2048 rows
    int g = tid & 127;
    float bs = bih0[j] + bhh0[j];
    if (g < V1){
      float a0=0.f, a1=0.f, a2=0.f, a3=0.f;
      const float* wr = wih0 + (size_t)j*512;
      for (int k=0;k<512;k+=4){
        a0 += wr[k]   * Wemb[(size_t)k*V1 + g];
        a1 += wr[k+1] * Wemb[(size_t)(k+1)*V1 + g];
        a2 += wr[k+2] * Wemb[(size_t)(k+2)*V1 + g];
        a3 += wr[k+3] * Wemb[(size_t)(k+3)*V1 + g];
      }
      M0[(size_t)j*112 + g] = ((a0+a1)+(a2+a3)) + bs;
    } else if (g == V1){
      M0[(size_t)j*112 + V1] = bs;
    }
  } else {
    int b2 = bid - 7902;                // 225 blocks
    if (b2 < 192)      st[b2*256 + tid] = 0.f;
    else if (b2 < 224) h1hist[(b2-192)*256 + tid] = 0u;
    else if (tid < 8)  bar[tid*32] = 0u;
  }
}

// ---------------- MFMA conv (unchanged): 256 wgs, wg=(M 64 pos)x(N 256 a) ----------------
__global__ __launch_bounds__(256) void k_convm(const ushortT* __restrict__ fT,
                                               const ushortT* __restrict__ wb,
                                               const float* __restrict__ bfv,
                                               ushortT* __restrict__ fpj)
{
  __shared__ __align__(16) ushortT a_lds[136*72];
  __shared__ __align__(16) ushortT b_lds[256*72];
  const int tid = threadIdx.x;
  const int w   = tid >> 6;
  const int l   = tid & 63;
  const int kg  = l >> 4;
  const int ln  = l & 15;
  const int bid = blockIdx.x;
  const int nh  = bid & 1;
  const int mt  = bid >> 1;
  const int b   = mt >> 2;
  const int y0  = (mt & 3) * 2;
  const int a0  = nh * 256;

  f32x4 acc[4][4];
  #pragma unroll
  for (int nb=0; nb<4; nb++){
    float bv = bfv[a0 + w*64 + nb*16 + ln];
    #pragma unroll
    for (int mb=0; mb<4; mb++){
      acc[mb][nb][0]=bv; acc[mb][nb][1]=bv; acc[mb][nb][2]=bv; acc[mb][nb][3]=bv;
    }
  }

  const char* aSrc = (const char*)(fT + (((size_t)b*10 + y0)*34)*512);
  const char* wSrc = (const char*)wb;

  for (int c0 = 0; c0 < 512; c0 += 64){
    {
      const char* s = aSrc + (size_t)c0*2;
      #pragma unroll
      for (int i=0;i<4;i++){
        int idx = tid + i*256;
        int pos = idx >> 3, q = idx & 7;
        uint4 v = *(const uint4*)(s + (size_t)pos*1024 + q*16);
        *(uint4*)((char*)a_lds + pos*144 + q*16) = v;
      }
      if (tid < 64){
        int idx = 1024 + tid;
        int pos = idx >> 3, q = idx & 7;
        uint4 v = *(const uint4*)(s + (size_t)pos*1024 + q*16);
        *(uint4*)((char*)a_lds + pos*144 + q*16) = v;
      }
    }
    #pragma unroll
    for (int t=0; t<9; t++){
      const int ky = t/3, kx = t - (t/3)*3;
      {
        const char* s = wSrc + (((size_t)t*512 + a0)*512 + c0)*2;
        #pragma unroll
        for (int i=0;i<8;i++){
          int idx = tid + i*256;
          int ai = idx >> 3, q = idx & 7;
          uint4 v = *(const uint4*)(s + (size_t)ai*1024 + q*16);
          *(uint4*)((char*)b_lds + ai*144 + q*16) = v;
        }
      }
      __syncthreads();
      #pragma unroll
      for (int ks=0; ks<2; ks++){
        bf16x8 afr[4], bfr[4];
        #pragma unroll
        for (int mb=0; mb<4; mb++){
          int row = ((mb>>1) + ky)*34 + (mb&1)*16 + ln + kx;
          afr[mb] = *(const bf16x8*)((const char*)a_lds + row*144 + kg*16 + ks*64);
        }
        #pragma unroll
        for (int nb=0; nb<4; nb++){
          int ai = w*64 + nb*16 + ln;
          bfr[nb] = *(const bf16x8*)((const char*)b_lds + ai*144 + kg*16 + ks*64);
        }
        #pragma unroll
        for (int mb=0; mb<4; mb++)
          #pragma unroll
          for (int nb=0; nb<4; nb++)
            acc[mb][nb] = __builtin_amdgcn_mfma_f32_16x16x32_bf16(afr[mb], bfr[nb], acc[mb][nb], 0, 0, 0);
      }
      __syncthreads();
    }
  }

  #pragma unroll
  for (int mb=0; mb<4; mb++){
    #pragma unroll
    for (int nb=0; nb<4; nb++){
      int a = a0 + w*64 + nb*16 + ln;
      #pragma unroll
      for (int r4=0; r4<4; r4++){
        int pos = mb*16 + kg*4 + r4;
        fpj[((size_t)b*HWP + (y0*32 + pos))*512 + a] = f2b(acc[mb][nb][r4]);
      }
    }
  }
}

// ---------------- stage bf16 state [32 b][256 uints] MALL -> LDS [32][268] ----------------
__device__ __forceinline__ void stage_state_s(uintT* __restrict__ hs,
                                              const uintT* __restrict__ src, int tid){
  #pragma unroll
  for (int i=0;i<16;i++){
    int g = tid + i*512;
    hs[(g >> 8)*268 + (g & 255)] = sload_u(&src[g]);
  }
}

// ---------------- cumulative fence-free grid barrier (system scope) ----------------
__device__ __forceinline__ void sysbar(uintT* bar, int it, int bid){
  __syncthreads();   // vmcnt(0) drain: all block's system stores acked at MALL
  if (threadIdx.x == 0){
    __hip_atomic_fetch_add(bar + (bid & 7)*32, 1u, __ATOMIC_RELAXED, __HIP_MEMORY_SCOPE_SYSTEM);
    const uintT tgt = (uintT)(it + 1) * (uintT)NWG;
    for (;;){
      uintT s = 0;
      #pragma unroll
      for (int i=0;i<8;i++)
        s += __hip_atomic_load(bar + i*32, __ATOMIC_RELAXED, __HIP_MEMORY_SCOPE_SYSTEM);
      if (s >= tgt) break;
      __builtin_amdgcn_s_sleep(8);
    }
  }
  __syncthreads();
}

// ---------------- persistent pipeline: 64 A + 64 B + 32 C(att) blocks ----------------
__global__ __launch_bounds__(512) void k_main(
    const int* __restrict__ gt, const float* __restrict__ M0,
    const uintT* __restrict__ wgb,
    const float* __restrict__ bih1, const float* __restrict__ bhh1,
    float* __restrict__ st, uintT* __restrict__ h1hist, uintT* __restrict__ bar,
    const float* __restrict__ features, const ushortT* __restrict__ fpj,
    const uintT* __restrict__ WstTb, const float* __restrict__ watt,
    const uintT* __restrict__ Woutb, const float* __restrict__ bout,
    float* __restrict__ out)
{
  __shared__ __align__(16) float pool[POOLF];
  const int tid = threadIdx.x, bid = blockIdx.x;
  uintT* h0bf = (uintT*)st;            // 2 parities x [32 b][256 u] bf16
  float* c0T  = st + 16384;            // [512][32] block-private
  float* c1T  = st + 32768;            // [512][32] block-private

  const bool isGate = bid < 128;
  const bool isA    = bid < 64;

  // ---- gate-role constants + weights hoisted to VGPRs ----
  const int w   = tid >> 6;
  const int l   = tid & 63;
  const int kg  = l >> 4;
  const int ln  = l & 15;
  const int ks2 = w >> 2;
  const int rt  = (w >> 1) & 1;
  const int nh  = w & 1;
  const int u0  = (isA ? bid : bid - 64) * 8;
  const int jrow = (ln >> 2)*512 + u0 + rt*4 + (ln & 3);

  uint4 wA[8], wB1[8], wB2[8];
  if (isGate){
    if (isA){
      const uintT* wp = wgb + (size_t)jrow*256 + kg*4;            // whh0
      #pragma unroll
      for (int s8=0; s8<8; s8++) wA[s8] = *(const uint4*)(wp + (ks2*8 + s8)*16);
    } else {
      const uintT* wp1 = wgb + 524288  + (size_t)jrow*256 + kg*4; // wih1
      const uintT* wp2 = wgb + 1048576 + (size_t)jrow*256 + kg*4; // whh1
      #pragma unroll
      for (int s8=0; s8<8; s8++){
        wB1[s8] = *(const uint4*)(wp1 + (ks2*8 + s8)*16);
        wB2[s8] = *(const uint4*)(wp2 + (ks2*8 + s8)*16);
      }
    }
  } else {
    pool[1024 + tid] = watt[tid];      // watts: persistent across iterations
  }

  uintT* hs = (uintT*)pool;            // [32][268] staged state (A/B)
  float* gs = pool + 8576;             // [2][32][33] partial D (A/B)
  float* hv = pool + 10688;            // [8][33] new h staging (A/B)
  const ushortT* hb = (const ushortT*)hs + (nh*16 + ln)*536 + kg*8;

  for (int L = 0; L <= STEPS + 1; L++){
    if (isGate){
      const int t = isA ? L : L - 1;
      if (t >= 0 && t <= STEPS-1){
        f32x4 acc = {0.f, 0.f, 0.f, 0.f};
        if (isA){
          stage_state_s(hs, h0bf + ((t+1)&1)*8192, tid);
          __syncthreads();
          #pragma unroll
          for (int s8=0; s8<8; s8++){
            int s = ks2*8 + s8;
            bf16x8 bfr = *(const bf16x8*)(hb + s*32);
            acc = __builtin_amdgcn_mfma_f32_16x16x32_bf16(u4_to_b8(wA[s8]), bfr, acc, 0, 0, 0);
          }
        } else {
          stage_state_s(hs, h0bf + (t&1)*8192, tid);
          __syncthreads();
          #pragma unroll
          for (int s8=0; s8<8; s8++){
            int s = ks2*8 + s8;
            bf16x8 bfr = *(const bf16x8*)(hb + s*32);
            acc = __builtin_amdgcn_mfma_f32_16x16x32_bf16(u4_to_b8(wB1[s8]), bfr, acc, 0, 0, 0);
          }
          __syncthreads();
          stage_state_s(hs, h1hist + (size_t)t*8192, tid);
          __syncthreads();
          #pragma unroll
          for (int s8=0; s8<8; s8++){
            int s = ks2*8 + s8;
            bf16x8 bfr = *(const bf16x8*)(hb + s*32);
            acc = __builtin_amdgcn_mfma_f32_16x16x32_bf16(u4_to_b8(wB2[s8]), bfr, acc, 0, 0, 0);
          }
        }
        #pragma unroll
        for (int r=0;r<4;r++)
          gs[(ks2*32 + kg*8 + rt*4 + r)*33 + nh*16 + ln] = acc[r];
        __syncthreads();

        if (tid < 256){
          const int ul = tid >> 5, b = tid & 31, u = u0 + ul;
          float g4[4];
          #pragma unroll
          for (int g=0; g<4; g++){
            float sacc = gs[(g*8+ul)*33 + b] + gs[(32 + g*8+ul)*33 + b];
            int j = g*512 + u;
            if (isA){
              int sym = (t > 0) ? gt[b*STEPS + t - 1] : V1;
              sacc += M0[(size_t)j*112 + sym];
            } else {
              sacc += bih1[j] + bhh1[j];
            }
            g4[g] = sacc;
          }
          float* cT = isA ? c0T : c1T;
          int idx = u*32 + b;
          float cn = sigf(g4[1])*cT[idx] + sigf(g4[0])*tanh_f(g4[2]);
          cT[idx] = cn;                               // block-private, plain
          float h = sigf(g4[3])*tanh_f(cn);
          hv[ul*33 + b] = h;
        }
        __syncthreads();
        if (tid < 128){
          const int up = tid >> 5, b = tid & 31;
          uintT v = packbf(hv[(up*2)*33 + b], hv[(up*2+1)*33 + b]);
          if (isA) sstore_u(&h0bf[(t&1)*8192 + b*256 + (u0>>1) + up], v);
          else     sstore_u(&h1hist[(size_t)(t+1)*8192 + b*256 + (u0>>1) + up], v);
        }
      }
    } else {
      // ======= role C: attention(rs), rs = L-2 (r14 k_att body) =======
      const int rs = L - 2;
      if (rs >= 0 && rs <= STEPS-1){
        const int b = bid - 128;
        float* h1s   = pool;            // 512
        float* spsl  = pool + 512;      // 512
        float* watts = pool + 1024;     // 512 (persistent)
        float* pals  = pool + 1536;     // 512
        float* attw  = pool + 2048;     // 256
        float* glim  = pool + 2304;     // 512
        float* red   = pool + 2816;     // 64
        float* opart = pool + 2880;     // 512
        float* sppt  = pool + 3392;     // 4096 (8 uq x 512 a)

        if (tid < 256){
          uintT hvw = sload_u(&h1hist[(size_t)(rs+1)*8192 + b*256 + tid]);  // h1(rs)
          h1s[2*tid]   = blo(hvw);
          h1s[2*tid+1] = bhi(hvw);
        }
        __syncthreads();

        // sp partials: 8 u-ranges x 512 a; uint4 weight loads (64/thread)
        {
          int ap4 = tid & 63, uq = tid >> 6;
          float a8[8] = {0.f,0.f,0.f,0.f,0.f,0.f,0.f,0.f};
          const uint4* wp = (const uint4*)(WstTb + (size_t)(uq*64)*256) + ap4;
          const float* hq = h1s + uq*64;
          #pragma unroll 8
          for (int u=0; u<64; u++){
            uint4 q = wp[(size_t)u*64];
            float h = hq[u];
            a8[0] += blo(q.x)*h; a8[1] += bhi(q.x)*h;
            a8[2] += blo(q.y)*h; a8[3] += bhi(q.y)*h;
            a8[4] += blo(q.z)*h; a8[5] += bhi(q.z)*h;
            a8[6] += blo(q.w)*h; a8[7] += bhi(q.w)*h;
          }
          #pragma unroll
          for (int j=0;j<8;j++) sppt[uq*512 + ap4*8 + j] = a8[j];
        }
        __syncthreads();
        {
          float s = 0.f;
          #pragma unroll
          for (int uq=0;uq<8;uq++) s += sppt[uq*512 + tid];
          spsl[tid] = s;
        }
        __syncthreads();

        // attention logits over (p, a-half)
        {
          int p = tid & 255, ac = tid >> 8;
          const uint4* fr = (const uint4*)(fpj + ((size_t)b*HWP + p)*512 + ac*256);
          float al2 = 0.f;
          #pragma unroll 8
          for (int kb=0;kb<32;kb++){
            uint4 q = fr[kb];
            float v[8] = {blo(q.x),bhi(q.x),blo(q.y),bhi(q.y),blo(q.z),bhi(q.z),blo(q.w),bhi(q.w)};
            int a0 = ac*256 + kb*8;
            #pragma unroll
            for (int i=0;i<8;i++)
              al2 += watts[a0+i] * tanh_f(v[i] + spsl[a0+i]);
          }
          pals[tid] = al2;
        }
        __syncthreads();
        // softmax over 256 positions
        {
          float al2 = (tid < 256) ? (pals[tid] + pals[256+tid]) : -1e30f;
          float m = al2;
          #pragma unroll
          for (int off=32; off>0; off>>=1) m = fmaxf(m, __shfl_xor(m, off));
          if (tid < 256 && (tid & 63)==0) red[tid>>6] = m;
          __syncthreads();
          m = fmaxf(fmaxf(red[0],red[1]), fmaxf(red[2],red[3]));
          float e = (tid < 256) ? __expf(al2 - m) : 0.f;
          float s = e;
          #pragma unroll
          for (int off=32; off>0; off>>=1) s += __shfl_xor(s, off);
          __syncthreads();
          if (tid < 256 && (tid & 63)==0) red[tid>>6] = s;
          __syncthreads();
          if (tid < 256){
            float sa = red[0]+red[1]+red[2]+red[3];
            attw[tid] = e / sa;
          }
        }
        __syncthreads();
        // glimpse[c] = sum_p features[b,c,p] * attw[p]  (f32 direct)
        {
          const float4* fr = (const float4*)(features + ((size_t)b*512 + tid)*256);
          float acc = 0.f;
          #pragma unroll 8
          for (int kb=0;kb<64;kb++){
            float4 v = fr[kb];
            const float* aw = attw + kb*4;
            acc += v.x*aw[0] + v.y*aw[1] + v.z*aw[2] + v.w*aw[3];
          }
          glim[tid] = acc;
        }
        __syncthreads();
        // logits = [h1, glimpse] @ Wout^T + b_out; 4x parallel over k-quarters
        {
          int q = tid >> 7, o = tid & 127;
          float acc = 0.f;
          if (o < V1){
            const uint4* wr4 = (const uint4*)(Woutb + (size_t)o*512 + q*128);
            const float* src = (q < 2) ? (h1s + q*256) : (glim + (q-2)*256);
            #pragma unroll 8
            for (int kb=0;kb<32;kb++){
              uint4 w4 = wr4[kb];
              const float* sx = src + kb*8;
              acc += blo(w4.x)*sx[0] + bhi(w4.x)*sx[1] + blo(w4.y)*sx[2] + bhi(w4.y)*sx[3]
                   + blo(w4.z)*sx[4] + bhi(w4.z)*sx[5] + blo(w4.w)*sx[6] + bhi(w4.w)*sx[7];
            }
          }
          opart[tid] = acc;
        }
        __syncthreads();
        if (tid < V1){
          float acc = bout[tid] + opart[tid] + opart[128+tid] + opart[256+tid] + opart[384+tid];
          out[(size_t)b*STEPS*V1 + (size_t)rs*V1 + tid] = acc;
        }
      }
    }
    if (L <= STEPS) sysbar(bar, L, bid);
  }
}

extern "C" void kernel_launch(void* const* d_in, const int* in_sizes, int n_in,
                              void* d_out, int out_size, void* d_ws, size_t ws_size,
                              hipStream_t stream)
{
  const float* features = (const float*)d_in[0];
  const int*   gt       = (const int*)d_in[2];
  const float* Wf    = (const float*)d_in[3];
  const float* bfv   = (const float*)d_in[4];
  const float* Wst   = (const float*)d_in[5];
  const float* watt  = (const float*)d_in[6];
  const float* Wemb  = (const float*)d_in[7];
  const float* wih0  = (const float*)d_in[8];
  const float* whh0  = (const float*)d_in[9];
  const float* bih0  = (const float*)d_in[10];
  const float* bhh0  = (const float*)d_in[11];
  const float* wih1  = (const float*)d_in[12];
  const float* whh1  = (const float*)d_in[13];
  const float* bih1  = (const float*)d_in[14];
  const float* bhh1  = (const float*)d_in[15];
  const float* Wout  = (const float*)d_in[16];
  const float* bout  = (const float*)d_in[17];
  float* out = (float*)d_out;

  // ---- workspace layout (bytes), max extent 25,133,056 (proven footprint) ----
  char* wsb = (char*)d_ws;
  ushortT* fpj    = (ushortT*)(wsb + 0);          //  8,388,608 persist
  uintT*   h1hist = (uintT*)  (wsb + 8388608);    //  1,048,576 (32 slots x 32KB; slot0 = zeros)
  float*   M0     = (float*)  (wsb + 16777216);   //    917,504 (incl. bias col 111)
  uintT*   wgb    = (uintT*)  (wsb + 17694720);   //  6,291,456 (whh0|wih1|whh1 bf16)
  uintT*   Woutb  = (uintT*)  (wsb + 23986176);   //    227,328 (ends 24,213,504)
  uintT*   bar    = (uintT*)  (wsb + 24213504);   //      1,024 (8 counters x 128B)
  uintT*   WstTb  = (uintT*)  (wsb + 24215552);   //    524,288
  float*   st     = (float*)  (wsb + 24739840);   //    196,608 (h0bf x2, c0, c1)
  // transients (dead after k_convm; overlay h1hist/M0/wgb/Woutb/bar/WstTb):
  uintT*   fTt    = (uintT*)  (wsb + 8388608);    // 11,141,120 bf16 featTp
  ushortT* wbt    = (ushortT*)(wsb + 19529728);   //  4,718,592 bf16 wb[t][a][c] (ends 24,248,320)

  k_pre  <<<15488, 256, 0, stream>>>(features, Wf, fTt, (uintT*)wbt);
  k_convm<<<256,   256, 0, stream>>>((const ushortT*)fTt, wbt, bfv, fpj);
  // k_post overlays conv transients -> must run AFTER k_convm
  k_post <<<8127,  256, 0, stream>>>(whh0, wih1, whh1, wgb,
                                     Wst, WstTb, Wout, Woutb,
                                     wih0, Wemb, bih0, bhh0, M0,
                                     st, h1hist, bar);
  k_main <<<NWG,   512, 0, stream>>>(gt, M0, wgb, bih1, bhh1, st, h1hist, bar,
                                     features, fpj, WstTb, watt, Woutb, bout, out);
  (void)in_sizes; (void)n_in; (void)out_size; (void)ws_size;
}

// Round 9
// 673.709 us; speedup vs baseline: 2.6806x; 2.6806x over previous
//
#include <hip/hip_runtime.h>
#include <hip/hip_bf16.h>

// SARDecoder round 17: REVERT r16 (lockstep+heterogeneous roles = pay max
// role latency/iter; C serialized = +30us/iter, FETCH 12->109MB). Base = r15
// (757us verified). New: k_rec lockstep sysbar -> per-group DATAFLOW counters
// (same verified system-scope release protocol: vmcnt-drain then add; MALL-
// coherent counters+state). A depends only on A (h0 chain, full 32-slot
// history); B polls arrA[t] & arrB[t-1]. No role waits on a slower role.
// Role B: 4 phases -> 2 (stage h0+h1 concurrently into 2 LDS buffers, 78KB;
// waves split by MATRIX full-K: 16 MFMA each, identical totals+reduce).
// k_pre / k_convm / k_att byte-identical to r15.

#define RNN   512
#define V1    111
#define STEPS 31
#define HWP   256
#define NWG   128

typedef unsigned short ushortT;
typedef unsigned int   uintT;
typedef __attribute__((ext_vector_type(8))) short bf16x8;   // 8 bf16 (4 VGPRs)
typedef __attribute__((ext_vector_type(4))) float f32x4;

__device__ __forceinline__ float blo(uintT u){ union { uintT i; float f; } v; v.i = u << 16; return v.f; }
__device__ __forceinline__ float bhi(uintT u){ union { uintT i; float f; } v; v.i = u & 0xffff0000u; return v.f; }
__device__ __forceinline__ ushortT f2b(float f){
  __hip_bfloat16 h = __float2bfloat16(f);
  union { __hip_bfloat16 b; ushortT s; } v; v.b = h; return v.s;
}
__device__ __forceinline__ uintT packbf(float lo, float hi){
  return (uintT)f2b(lo) | ((uintT)f2b(hi) << 16);
}
__device__ __forceinline__ bf16x8 u4_to_b8(uint4 u){
  union { uint4 a; bf16x8 b; } v; v.a = u; return v.b;
}
__device__ __forceinline__ float sigf(float x){ return 1.f/(1.f + __expf(-x)); }
__device__ __forceinline__ float tanh_f(float x){ float e = __expf(2.f*x); return 1.f - 2.f/(e+1.f); }

// ---- SYSTEM-scope relaxed atomics: bypass L2 both directions (MALL-coherent) ----
__device__ __forceinline__ uintT sload_u(const uintT* p){
  return __hip_atomic_load((uintT*)p, __ATOMIC_RELAXED, __HIP_MEMORY_SCOPE_SYSTEM);
}
__device__ __forceinline__ void sstore_u(uintT* p, uintT v){
  __hip_atomic_store(p, v, __ATOMIC_RELAXED, __HIP_MEMORY_SCOPE_SYSTEM);
}
__device__ __forceinline__ void wait_ge(uintT* p, uintT tgt){
  for (;;){
    if (__hip_atomic_load(p, __ATOMIC_RELAXED, __HIP_MEMORY_SCOPE_SYSTEM) >= tgt) break;
    __builtin_amdgcn_s_sleep(2);
  }
}

// ---------------- k_pre: featT (bid<10880) + tconv2 (grid 15488) ----------------
__global__ __launch_bounds__(256) void k_pre(const float* __restrict__ feat,
                                             const float* __restrict__ Wf,
                                             uintT* __restrict__ fT,
                                             uintT* __restrict__ wb){
  const int bid = blockIdx.x, tid = threadIdx.x;
  if (bid < 10880){
    int idx = bid*256 + tid;
    int cp = idx & 255;
    int r  = idx >> 8;
    int xi = r % 34;
    int q  = r / 34;
    int yy = q % 10;
    int b  = q / 10;
    float v0 = 0.f, v1 = 0.f;
    if (yy >= 1 && yy <= 8 && xi >= 1 && xi <= 32){
      size_t base = (((size_t)b*512 + 2*cp)*8 + (yy-1))*32 + (xi-1);
      v0 = feat[base];
      v1 = feat[base + 256];
    }
    fT[idx] = packbf(v0, v1);
  } else {
    int idx = (bid - 10880)*256 + tid;   // 1,179,648
    int cp = idx & 255;
    int r  = idx >> 8;
    int a  = r & 511;
    int t  = r >> 9;
    float v0 = Wf[((size_t)a*512 + 2*cp)*9 + t];
    float v1 = Wf[((size_t)a*512 + 2*cp + 1)*9 + t];
    wb[idx] = packbf(v0, v1);
  }
}

// ---------------- k_post: wgate | wstT | woutb | m0 | init (grid 8102) ----------------
__global__ __launch_bounds__(256) void k_post(
    const float* __restrict__ w0, const float* __restrict__ w1,
    const float* __restrict__ w2, uintT* __restrict__ wgb,
    const float* __restrict__ Wst, uintT* __restrict__ WstTb,
    const float* __restrict__ Wout, uintT* __restrict__ Woutb,
    const float* __restrict__ wih0, const float* __restrict__ Wemb,
    const float* __restrict__ bih0, const float* __restrict__ bhh0,
    float* __restrict__ M0,
    float* __restrict__ st, uintT* __restrict__ h1hist,
    uintT* __restrict__ h0hist, uintT* __restrict__ bar)
{
  const int bid = blockIdx.x, tid = threadIdx.x;
  if (bid < 6144){
    int idx = bid*256 + tid;            // 1,572,864
    int m = idx >> 19, r = idx & 524287;
    const float* s = (m==0)? w0 : (m==1)? w1 : w2;
    float2 v = *(const float2*)(s + 2*(size_t)r);
    wgb[idx] = packbf(v.x, v.y);
  } else if (bid < 6656){
    int idx = (bid-6144)*256 + tid;     // 131,072
    int u = idx >> 8, ap = idx & 255;
    WstTb[idx] = packbf(Wst[(size_t)(2*ap)*512 + u], Wst[(size_t)(2*ap+1)*512 + u]);
  } else if (bid < 6878){
    int idx = (bid-6656)*256 + tid;     // 56,832
    float2 v = *(const float2*)(Wout + 2*(size_t)idx);
    Woutb[idx] = packbf(v.x, v.y);
  } else if (bid < 7902){
    int j = (bid-6878)*2 + (tid >> 7);  // 2048 rows
    int g = tid & 127;
    float bs = bih0[j] + bhh0[j];
    if (g < V1){
      float a0=0.f, a1=0.f, a2=0.f, a3=0.f;
      const float* wr = wih0 + (size_t)j*512;
      for (int k=0;k<512;k+=4){
        a0 += wr[k]   * Wemb[(size_t)k*V1 + g];
        a1 += wr[k+1] * Wemb[(size_t)(k+1)*V1 + g];
        a2 += wr[k+2] * Wemb[(size_t)(k+2)*V1 + g];
        a3 += wr[k+3] * Wemb[(size_t)(k+3)*V1 + g];
      }
      M0[(size_t)j*112 + g] = ((a0+a1)+(a2+a3)) + bs;
    } else if (g == V1){
      M0[(size_t)j*112 + V1] = bs;
    }
  } else {
    int b2 = bid - 7902;                // 200 blocks
    if (b2 < 128)      st[b2*256 + tid] = 0.f;                   // c0,c1
    else if (b2 < 160) h1hist[(b2-128)*256 + tid] = 0u;          // slot 0
    else if (b2 < 192) h0hist[(b2-160)*256 + tid] = 0u;          // slot 0
    else               bar[(b2-192)*256 + tid] = 0u;             // arrA|arrB
  }
}

// ---------------- MFMA conv (unchanged): 256 wgs, wg=(M 64 pos)x(N 256 a) ----------------
__global__ __launch_bounds__(256) void k_convm(const ushortT* __restrict__ fT,
                                               const ushortT* __restrict__ wb,
                                               const float* __restrict__ bfv,
                                               ushortT* __restrict__ fpj)
{
  __shared__ __align__(16) ushortT a_lds[136*72];
  __shared__ __align__(16) ushortT b_lds[256*72];
  const int tid = threadIdx.x;
  const int w   = tid >> 6;
  const int l   = tid & 63;
  const int kg  = l >> 4;
  const int ln  = l & 15;
  const int bid = blockIdx.x;
  const int nh  = bid & 1;
  const int mt  = bid >> 1;
  const int b   = mt >> 2;
  const int y0  = (mt & 3) * 2;
  const int a0  = nh * 256;

  f32x4 acc[4][4];
  #pragma unroll
  for (int nb=0; nb<4; nb++){
    float bv = bfv[a0 + w*64 + nb*16 + ln];
    #pragma unroll
    for (int mb=0; mb<4; mb++){
      acc[mb][nb][0]=bv; acc[mb][nb][1]=bv; acc[mb][nb][2]=bv; acc[mb][nb][3]=bv;
    }
  }

  const char* aSrc = (const char*)(fT + (((size_t)b*10 + y0)*34)*512);
  const char* wSrc = (const char*)wb;

  for (int c0 = 0; c0 < 512; c0 += 64){
    {
      const char* s = aSrc + (size_t)c0*2;
      #pragma unroll
      for (int i=0;i<4;i++){
        int idx = tid + i*256;
        int pos = idx >> 3, q = idx & 7;
        uint4 v = *(const uint4*)(s + (size_t)pos*1024 + q*16);
        *(uint4*)((char*)a_lds + pos*144 + q*16) = v;
      }
      if (tid < 64){
        int idx = 1024 + tid;
        int pos = idx >> 3, q = idx & 7;
        uint4 v = *(const uint4*)(s + (size_t)pos*1024 + q*16);
        *(uint4*)((char*)a_lds + pos*144 + q*16) = v;
      }
    }
    #pragma unroll
    for (int t=0; t<9; t++){
      const int ky = t/3, kx = t - (t/3)*3;
      {
        const char* s = wSrc + (((size_t)t*512 + a0)*512 + c0)*2;
        #pragma unroll
        for (int i=0;i<8;i++){
          int idx = tid + i*256;
          int ai = idx >> 3, q = idx & 7;
          uint4 v = *(const uint4*)(s + (size_t)ai*1024 + q*16);
          *(uint4*)((char*)b_lds + ai*144 + q*16) = v;
        }
      }
      __syncthreads();
      #pragma unroll
      for (int ks=0; ks<2; ks++){
        bf16x8 afr[4], bfr[4];
        #pragma unroll
        for (int mb=0; mb<4; mb++){
          int row = ((mb>>1) + ky)*34 + (mb&1)*16 + ln + kx;
          afr[mb] = *(const bf16x8*)((const char*)a_lds + row*144 + kg*16 + ks*64);
        }
        #pragma unroll
        for (int nb=0; nb<4; nb++){
          int ai = w*64 + nb*16 + ln;
          bfr[nb] = *(const bf16x8*)((const char*)b_lds + ai*144 + kg*16 + ks*64);
        }
        #pragma unroll
        for (int mb=0; mb<4; mb++)
          #pragma unroll
          for (int nb=0; nb<4; nb++)
            acc[mb][nb] = __builtin_amdgcn_mfma_f32_16x16x32_bf16(afr[mb], bfr[nb], acc[mb][nb], 0, 0, 0);
      }
      __syncthreads();
    }
  }

  #pragma unroll
  for (int mb=0; mb<4; mb++){
    #pragma unroll
    for (int nb=0; nb<4; nb++){
      int a = a0 + w*64 + nb*16 + ln;
      #pragma unroll
      for (int r4=0; r4<4; r4++){
        int pos = mb*16 + kg*4 + r4;
        fpj[((size_t)b*HWP + (y0*32 + pos))*512 + a] = f2b(acc[mb][nb][r4]);
      }
    }
  }
}

// ---------------- stage bf16 state [32 b][256 uints] MALL -> LDS [32][268] ----------------
__device__ __forceinline__ void stage_state_s(uintT* __restrict__ hs,
                                              const uintT* __restrict__ src, int tid){
  #pragma unroll
  for (int i=0;i<16;i++){
    int g = tid + i*512;
    hs[(g >> 8)*268 + (g & 255)] = sload_u(&src[g]);
  }
}

// ---------------- dataflow recurrence: 64 A + 64 B blocks, per-group counters ----------------
__global__ __launch_bounds__(512) void k_rec(
    const int* __restrict__ gt, const float* __restrict__ M0,
    const uintT* __restrict__ wgb,
    const float* __restrict__ bih1, const float* __restrict__ bhh1,
    float* __restrict__ st, uintT* __restrict__ h1hist,
    uintT* __restrict__ h0hist, uintT* __restrict__ bar)
{
  // pool: hs0 [32][268]u | hs1 [32][268]u | gs [2][32][33]f | hv [8][33]f
  __shared__ __align__(16) float pool[19584];
  const int tid = threadIdx.x, bid = blockIdx.x;
  float* c0T = st;                     // [512][32] block-private slice
  float* c1T = st + 16384;
  uintT* arrA = bar;                   // arrA[t] at bar[t*32]   (128B lines)
  uintT* arrB = bar + 1024;            // arrB[t] at bar[1024 + t*32]

  const bool isA = bid < 64;
  const int w   = tid >> 6;
  const int l   = tid & 63;
  const int kg  = l >> 4;
  const int ln  = l & 15;
  const int ks2 = w >> 2;              // A: K-half | B: matrix select
  const int rt  = (w >> 1) & 1;
  const int nh  = w & 1;
  const int u0  = (isA ? bid : bid - 64) * 8;
  const int jrow = (ln >> 2)*512 + u0 + rt*4 + (ln & 3);

  uintT* hs0 = (uintT*)pool;                 // 8576 uints
  uintT* hs1 = (uintT*)pool + 8576;          // 8576 uints
  float* gs  = pool + 17152;                 // 2112 floats
  float* hv  = pool + 19264;                 // 264 floats
  const ushortT* hb0 = (const ushortT*)hs0 + (nh*16 + ln)*536 + kg*8;
  const ushortT* hb1 = (const ushortT*)hs1 + (nh*16 + ln)*536 + kg*8;

  // ---- weights hoisted to VGPRs (64 VGPR either role) ----
  uint4 wA[8], wB[16];
  if (isA){
    const uintT* wp = wgb + (size_t)jrow*256 + kg*4;            // whh0
    #pragma unroll
    for (int s8=0; s8<8; s8++) wA[s8] = *(const uint4*)(wp + (ks2*8 + s8)*16);
  } else {
    const uintT* wp = wgb + (ks2 ? 1048576 : 524288) + (size_t)jrow*256 + kg*4;
    #pragma unroll
    for (int s=0; s<16; s++) wB[s] = *(const uint4*)(wp + s*16);
  }

  for (int t = 0; t <= STEPS-1; t++){
    if (isA){
      // ======= role A: gates0(t) = whh0 @ h0(t-1); needs arrA[t-1] =======
      if (t > 0){
        if (tid == 0) wait_ge(arrA + (t-1)*32, 64u);
        __syncthreads();
      }
      stage_state_s(hs0, h0hist + (size_t)t*8192, tid);
      __syncthreads();
      f32x4 acc = {0.f, 0.f, 0.f, 0.f};
      #pragma unroll
      for (int s8=0; s8<8; s8++){
        int s = ks2*8 + s8;
        bf16x8 bfr = *(const bf16x8*)(hb0 + s*32);
        acc = __builtin_amdgcn_mfma_f32_16x16x32_bf16(u4_to_b8(wA[s8]), bfr, acc, 0, 0, 0);
      }
      #pragma unroll
      for (int r=0;r<4;r++)
        gs[(ks2*32 + kg*8 + rt*4 + r)*33 + nh*16 + ln] = acc[r];
      __syncthreads();
      if (tid < 256){
        const int ul = tid >> 5, b = tid & 31, u = u0 + ul;
        float g4[4];
        #pragma unroll
        for (int g=0; g<4; g++){
          float sacc = gs[(g*8+ul)*33 + b] + gs[(32 + g*8+ul)*33 + b];
          int j = g*512 + u;
          int sym = (t > 0) ? gt[b*STEPS + t - 1] : V1;
          g4[g] = sacc + M0[(size_t)j*112 + sym];
        }
        int idx = u*32 + b;
        float cn = sigf(g4[1])*c0T[idx] + sigf(g4[0])*tanh_f(g4[2]);
        c0T[idx] = cn;
        hv[ul*33 + b] = sigf(g4[3])*tanh_f(cn);
      }
      __syncthreads();
      if (tid < 128){
        const int up = tid >> 5, b = tid & 31;
        sstore_u(&h0hist[(size_t)(t+1)*8192 + b*256 + (u0>>1) + up],
                 packbf(hv[(up*2)*33 + b], hv[(up*2+1)*33 + b]));
      }
      __syncthreads();   // vmcnt drain: h0 stores acked at MALL
      if (tid == 0)
        __hip_atomic_fetch_add(arrA + t*32, 1u, __ATOMIC_RELAXED, __HIP_MEMORY_SCOPE_SYSTEM);
    } else {
      // ======= role B: gates1(t) = wih1@h0(t) + whh1@h1(t-1) =======
      if (tid == 0){
        wait_ge(arrA + t*32, 64u);                 // h0(t) ready
        if (t > 0) wait_ge(arrB + (t-1)*32, 64u);  // h1(t-1) ready
      }
      __syncthreads();
      stage_state_s(hs0, h0hist + (size_t)(t+1)*8192, tid);   // h0(t)
      stage_state_s(hs1, h1hist + (size_t)t*8192, tid);       // h1(t-1)
      __syncthreads();
      f32x4 acc = {0.f, 0.f, 0.f, 0.f};
      const ushortT* hbm = ks2 ? hb1 : hb0;
      #pragma unroll
      for (int s=0; s<16; s++){
        bf16x8 bfr = *(const bf16x8*)(hbm + s*32);
        acc = __builtin_amdgcn_mfma_f32_16x16x32_bf16(u4_to_b8(wB[s]), bfr, acc, 0, 0, 0);
      }
      #pragma unroll
      for (int r=0;r<4;r++)
        gs[(ks2*32 + kg*8 + rt*4 + r)*33 + nh*16 + ln] = acc[r];
      __syncthreads();
      if (tid < 256){
        const int ul = tid >> 5, b = tid & 31, u = u0 + ul;
        float g4[4];
        #pragma unroll
        for (int g=0; g<4; g++){
          float sacc = gs[(g*8+ul)*33 + b] + gs[(32 + g*8+ul)*33 + b];
          int j = g*512 + u;
          g4[g] = sacc + bih1[j] + bhh1[j];
        }
        int idx = u*32 + b;
        float cn = sigf(g4[1])*c1T[idx] + sigf(g4[0])*tanh_f(g4[2]);
        c1T[idx] = cn;
        hv[ul*33 + b] = sigf(g4[3])*tanh_f(cn);
      }
      __syncthreads();
      if (tid < 128){
        const int up = tid >> 5, b = tid & 31;
        sstore_u(&h1hist[(size_t)(t+1)*8192 + b*256 + (u0>>1) + up],
                 packbf(hv[(up*2)*33 + b], hv[(up*2+1)*33 + b]));
      }
      __syncthreads();   // vmcnt drain: h1 stores acked at MALL
      if (tid == 0)
        __hip_atomic_fetch_add(arrB + t*32, 1u, __ATOMIC_RELAXED, __HIP_MEMORY_SCOPE_SYSTEM);
    }
  }
}

// ---------------- phase 2: attention for all (b, r) in parallel (992 blocks) ----------------
__global__ __launch_bounds__(512) void k_att(
    const float* __restrict__ features, const uintT* __restrict__ h1hist,
    const ushortT* __restrict__ fpj, const uintT* __restrict__ WstTb,
    const float* __restrict__ watt, const uintT* __restrict__ Woutb,
    const float* __restrict__ bout, float* __restrict__ out)
{
  __shared__ __align__(16) float pool[7488];
  const int tid = threadIdx.x;
  const int b = blockIdx.x / STEPS, r = blockIdx.x % STEPS;
  float* h1s   = pool;            // 512
  float* spsl  = pool + 512;      // 512
  float* watts = pool + 1024;     // 512
  float* pals  = pool + 1536;     // 512
  float* attw  = pool + 2048;     // 256
  float* glim  = pool + 2304;     // 512
  float* red   = pool + 2816;     // 64
  float* opart = pool + 2880;     // 512
  float* sppt  = pool + 3392;     // 4096 (8 uq x 512 a)

  if (tid < 256){
    uintT hvw = h1hist[(size_t)(r+1)*8192 + b*256 + tid];  // h1(r)
    h1s[2*tid]   = blo(hvw);
    h1s[2*tid+1] = bhi(hvw);
  }
  watts[tid] = watt[tid];
  __syncthreads();

  // sp partials: 8 u-ranges x 512 a; uint4 weight loads (64/thread)
  {
    int ap4 = tid & 63, uq = tid >> 6;
    float a8[8] = {0.f,0.f,0.f,0.f,0.f,0.f,0.f,0.f};
    const uint4* wp = (const uint4*)(WstTb + (size_t)(uq*64)*256) + ap4;
    const float* hq = h1s + uq*64;
    #pragma unroll 8
    for (int u=0; u<64; u++){
      uint4 q = wp[(size_t)u*64];
      float h = hq[u];
      a8[0] += blo(q.x)*h; a8[1] += bhi(q.x)*h;
      a8[2] += blo(q.y)*h; a8[3] += bhi(q.y)*h;
      a8[4] += blo(q.z)*h; a8[5] += bhi(q.z)*h;
      a8[6] += blo(q.w)*h; a8[7] += bhi(q.w)*h;
    }
    #pragma unroll
    for (int j=0;j<8;j++) sppt[uq*512 + ap4*8 + j] = a8[j];
  }
  __syncthreads();
  {
    float s = 0.f;
    #pragma unroll
    for (int uq=0;uq<8;uq++) s += sppt[uq*512 + tid];
    spsl[tid] = s;
  }
  __syncthreads();

  // attention logits over (p, a-half)
  {
    int p = tid & 255, ac = tid >> 8;
    const uint4* fr = (const uint4*)(fpj + ((size_t)b*HWP + p)*512 + ac*256);
    float al2 = 0.f;
    #pragma unroll 8
    for (int kb=0;kb<32;kb++){
      uint4 q = fr[kb];
      float v[8] = {blo(q.x),bhi(q.x),blo(q.y),bhi(q.y),blo(q.z),bhi(q.z),blo(q.w),bhi(q.w)};
      int a0 = ac*256 + kb*8;
      #pragma unroll
      for (int i=0;i<8;i++)
        al2 += watts[a0+i] * tanh_f(v[i] + spsl[a0+i]);
    }
    pals[tid] = al2;
  }
  __syncthreads();
  // softmax over 256 positions
  {
    float al2 = (tid < 256) ? (pals[tid] + pals[256+tid]) : -1e30f;
    float m = al2;
    #pragma unroll
    for (int off=32; off>0; off>>=1) m = fmaxf(m, __shfl_xor(m, off));
    if (tid < 256 && (tid & 63)==0) red[tid>>6] = m;
    __syncthreads();
    m = fmaxf(fmaxf(red[0],red[1]), fmaxf(red[2],red[3]));
    float e = (tid < 256) ? __expf(al2 - m) : 0.f;
    float s = e;
    #pragma unroll
    for (int off=32; off>0; off>>=1) s += __shfl_xor(s, off);
    __syncthreads();
    if (tid < 256 && (tid & 63)==0) red[tid>>6] = s;
    __syncthreads();
    if (tid < 256){
      float sa = red[0]+red[1]+red[2]+red[3];
      attw[tid] = e / sa;
    }
  }
  __syncthreads();
  // glimpse[c] = sum_p features[b,c,p] * attw[p]  (f32 direct)
  {
    const float4* fr = (const float4*)(features + ((size_t)b*512 + tid)*256);
    float acc = 0.f;
    #pragma unroll 8
    for (int kb=0;kb<64;kb++){
      float4 v = fr[kb];
      const float* aw = attw + kb*4;
      acc += v.x*aw[0] + v.y*aw[1] + v.z*aw[2] + v.w*aw[3];
    }
    glim[tid] = acc;
  }
  __syncthreads();
  // logits = [h1, glimpse] @ Wout^T + b_out; 4x parallel over k-quarters
  {
    int q = tid >> 7, o = tid & 127;
    float acc = 0.f;
    if (o < V1){
      const uint4* wr4 = (const uint4*)(Woutb + (size_t)o*512 + q*128);
      const float* src = (q < 2) ? (h1s + q*256) : (glim + (q-2)*256);
      #pragma unroll 8
      for (int kb=0;kb<32;kb++){
        uint4 w4 = wr4[kb];
        const float* sx = src + kb*8;
        acc += blo(w4.x)*sx[0] + bhi(w4.x)*sx[1] + blo(w4.y)*sx[2] + bhi(w4.y)*sx[3]
             + blo(w4.z)*sx[4] + bhi(w4.z)*sx[5] + blo(w4.w)*sx[6] + bhi(w4.w)*sx[7];
      }
    }
    opart[tid] = acc;
  }
  __syncthreads();
  if (tid < V1){
    float acc = bout[tid] + opart[tid] + opart[128+tid] + opart[256+tid] + opart[384+tid];
    out[(size_t)b*STEPS*V1 + (size_t)r*V1 + tid] = acc;
  }
}

extern "C" void kernel_launch(void* const* d_in, const int* in_sizes, int n_in,
                              void* d_out, int out_size, void* d_ws, size_t ws_size,
                              hipStream_t stream)
{
  const float* features = (const float*)d_in[0];
  const int*   gt       = (const int*)d_in[2];
  const float* Wf    = (const float*)d_in[3];
  const float* bfv   = (const float*)d_in[4];
  const float* Wst   = (const float*)d_in[5];
  const float* watt  = (const float*)d_in[6];
  const float* Wemb  = (const float*)d_in[7];
  const float* wih0  = (const float*)d_in[8];
  const float* whh0  = (const float*)d_in[9];
  const float* bih0  = (const float*)d_in[10];
  const float* bhh0  = (const float*)d_in[11];
  const float* wih1  = (const float*)d_in[12];
  const float* whh1  = (const float*)d_in[13];
  const float* bih1  = (const float*)d_in[14];
  const float* bhh1  = (const float*)d_in[15];
  const float* Wout  = (const float*)d_in[16];
  const float* bout  = (const float*)d_in[17];
  float* out = (float*)d_out;

  // ---- workspace layout (bytes), max extent 25,133,056 (proven footprint) ----
  char* wsb = (char*)d_ws;
  ushortT* fpj    = (ushortT*)(wsb + 0);          //  8,388,608 persist
  uintT*   h1hist = (uintT*)  (wsb + 8388608);    //  1,048,576 (32 slots; slot0 zeros)
  uintT*   h0hist = (uintT*)  (wsb + 9437184);    //  1,048,576 (32 slots; slot0 zeros)
  float*   M0     = (float*)  (wsb + 16777216);   //    917,504 (incl. bias col 111)
  uintT*   wgb    = (uintT*)  (wsb + 17694720);   //  6,291,456 (whh0|wih1|whh1 bf16)
  uintT*   Woutb  = (uintT*)  (wsb + 23986176);   //    227,328
  uintT*   WstTb  = (uintT*)  (wsb + 24215552);   //    524,288
  float*   st     = (float*)  (wsb + 24739840);   //    131,072 (c0, c1)
  uintT*   bar    = (uintT*)  (wsb + 24936448);   //      8,192 (arrA | arrB, 128B lines)
  // transients (dead after k_convm; overlay h0/h1hist/M0/wgb/Woutb/WstTb):
  uintT*   fTt    = (uintT*)  (wsb + 8388608);    // 11,141,120 bf16 featTp
  ushortT* wbt    = (ushortT*)(wsb + 19529728);   //  4,718,592 bf16 wb[t][a][c]

  k_pre  <<<15488, 256, 0, stream>>>(features, Wf, fTt, (uintT*)wbt);
  k_convm<<<256,   256, 0, stream>>>((const ushortT*)fTt, wbt, bfv, fpj);
  // k_post overlays conv transients -> must run AFTER k_convm
  k_post <<<8102,  256, 0, stream>>>(whh0, wih1, whh1, wgb,
                                     Wst, WstTb, Wout, Woutb,
                                     wih0, Wemb, bih0, bhh0, M0,
                                     st, h1hist, h0hist, bar);
  k_rec  <<<NWG,   512, 0, stream>>>(gt, M0, wgb, bih1, bhh1, st,
                                     h1hist, h0hist, bar);
  k_att  <<<32*STEPS, 512, 0, stream>>>(features, h1hist, fpj, WstTb, watt,
                                        Woutb, bout, out);
  (void)in_sizes; (void)n_in; (void)out_size; (void)ws_size;
}